// Round 11
// baseline (12622.855 us; speedup 1.0000x reference)
//
#include <hip/hip_runtime.h>
#include <hip/hip_bf16.h>

// LSTMModel_with_theta: B=64, T=2048, H=256, 2-layer LSTM -> mean_t -> MLP.
//
// Round 11: r10 topology, three latency kills:
//  1) issue-at-top/check-late: L0 partner + L1 h1 loads issued right after the
//     top barrier (peers' stores get ~600cy to land) -> first-check passes;
//     r10 prefetched at end-of-step, racing the peers' publishes (guaranteed
//     stale -> one exposed reload RTT per step).
//  2) L1 gate gather via shfl_xor quad exchange (r5-verified decode) -> gbuf
//     LDS round-trip and its barrier gone (3 bars -> 2).
//  3) L0 x loads hoisted to step top (were exposed ~600cy before EW).
//  - Tagged self-sync data (tag=t+1)<<16|bf16, relaxed agent atomics only,
//    no vmcnt drains in-loop, coop once-per-WG staging, static reg indices.

#define BB 64
#define TT 2048
#define HH 256
#define D0 16
#define D1 4

typedef short s16x8 __attribute__((ext_vector_type(8)));
typedef float f32x4 __attribute__((ext_vector_type(4)));

__device__ inline unsigned short f2bf(float f) {
  unsigned u = __float_as_uint(f);
  u += 0x7fff + ((u >> 16) & 1);          // RNE
  return (unsigned short)(u >> 16);
}
__device__ inline float sigm(float x) { return 1.f / (1.f + __expf(-x)); }
__device__ inline float tanh_f(float x) { return 1.f - 2.f / (__expf(2.f * x) + 1.f); }

__device__ inline unsigned long long ld64(const unsigned int* p) {
  return __hip_atomic_load((const unsigned long long*)p, __ATOMIC_RELAXED,
                           __HIP_MEMORY_SCOPE_AGENT);
}
__device__ inline void st32(unsigned int* p, unsigned int v) {
  __hip_atomic_store(p, v, __ATOMIC_RELAXED, __HIP_MEMORY_SCOPE_AGENT);
}
__device__ inline void st32i(int* p, int v) {
  __hip_atomic_store(p, v, __ATOMIC_RELAXED, __HIP_MEMORY_SCOPE_AGENT);
}
__device__ inline int ld32i(const int* p) {
  return __hip_atomic_load(p, __ATOMIC_RELAXED, __HIP_MEMORY_SCOPE_AGENT);
}
__device__ inline void wg_bar() {
  asm volatile("s_waitcnt lgkmcnt(0)" ::: "memory");
  __builtin_amdgcn_sched_barrier(0);
  __builtin_amdgcn_s_barrier();
  __builtin_amdgcn_sched_barrier(0);
}

#define MFMA(a, b, c) __builtin_amdgcn_mfma_f32_16x16x32_bf16((a), (b), (c), 0, 0, 0)

__global__ void xt_kernel(const float* __restrict__ x, float* __restrict__ xT) {
  int i = blockIdx.x * 256 + threadIdx.x;   // 131072 total
  int b = i & 63, t = i >> 6;
  xT[(size_t)t * BB + b] = x[(size_t)b * TT + t];
}

__global__ __launch_bounds__(512, 1)
void lstm_kernel(const float* __restrict__ Wx0, const float* __restrict__ Wh0,
                 const float* __restrict__ b0v,
                 const float* __restrict__ Wx1, const float* __restrict__ Wh1,
                 const float* __restrict__ b1v,
                 const float* __restrict__ xT,
                 unsigned int* __restrict__ seqring,   // [4][D0][16][256] tagged u32
                 unsigned int* __restrict__ h1ring,    // [4][D1][16][256] tagged u32
                 float* __restrict__ hmean, int* prog)
{
  __shared__ __align__(16) char Ab [8192];       // [16 rows][256 units] bf16, swizzled
  __shared__ __align__(16) char Ab1[8192];       // L1: h1(t-1)

  const int tid  = threadIdx.x;
  const int lane = tid & 63;
  const int w    = tid >> 6;        // wave 0..7
  const int u16  = lane & 15;
  const int kgrp = lane >> 4;
  const int arow = lane & 15;
  const int bid  = blockIdx.x;

  if (bid < 8) {
    // ========== LAYER 0: 2 WGs/group x 128 units, K=256 ==========
    const int g = bid >> 1, ho = bid & 1, po = 1 - ho;
    const int U = ho * 128 + w * 16 + u16;       // lane's unit (all 4 gates)
    // bw by PHASE (static reg indices): [n*8+0..3]=own ks, [n*8+4..7]=partner ks
    s16x8 bw[32];
#pragma unroll
    for (int n = 0; n < 4; ++n)
#pragma unroll
      for (int ph = 0; ph < 2; ++ph)
#pragma unroll
        for (int i = 0; i < 4; ++i) {
          const int ks = (ph == 0 ? ho : po) * 4 + i;   // runtime, address-only
          const int col = n * 256 + U;
#pragma unroll
          for (int j = 0; j < 8; ++j)
            bw[n * 8 + ph * 4 + i][j] =
                (short)f2bf(Wh0[(size_t)(ks * 32 + kgrp * 8 + j) * 1024 + col]);
        }
    float bE[4], xE[4];
#pragma unroll
    for (int n = 0; n < 4; ++n) { bE[n] = b0v[n * 256 + U]; xE[n] = Wx0[n * 256 + U]; }

    unsigned int* sr = seqring + (size_t)g * D0 * 4096;
    const int srow = tid >> 5, spc = (tid & 31) * 4;    // partner stage: 4 u32/thread
    float cL[4] = {0.f, 0.f, 0.f, 0.f};

    for (int t = 0; t < TT; ++t) {
      if ((t & 7) == 0 && t >= 16 && tid < 4)           // L1 back-pressure (coarse)
        while (ld32i(&prog[(g * 4 + tid) * 16]) < t - 8) __builtin_amdgcn_s_sleep(8);
      wg_bar();   // top: EW(t-1) LDS writes visible

      // issue partner loads NOW (stores get own-MFMA time to land) + x loads
      unsigned long long q0 = 0, q1 = 0;
      const unsigned int* sb = sr + ((t - 1) & (D0 - 1)) * 4096 + srow * 256 + po * 128 + spc;
      if (t > 0) { q0 = ld64(sb); q1 = ld64(sb + 2); }
      float xr[4];
#pragma unroll
      for (int r = 0; r < 4; ++r) xr[r] = xT[(size_t)t * BB + g * 16 + kgrp * 4 + r];

      f32x4 acc[4] = {{0,0,0,0},{0,0,0,0},{0,0,0,0},{0,0,0,0}};
      if (t > 0) {
        // own-half MFMAs from LDS (cover the partner-load flight)
        s16x8 ao[4];
#pragma unroll
        for (int i = 0; i < 4; ++i) {
          const int ks = ho * 4 + i;
          ao[i] = *(const s16x8*)(Ab + ((arow * 512 + (ks * 32 + kgrp * 8) * 2) ^ ((arow & 7) << 4)));
        }
#pragma unroll
        for (int i = 0; i < 4; ++i)
#pragma unroll
          for (int n = 0; n < 4; ++n) acc[n] = MFMA(ao[i], bw[n * 8 + i], acc[n]);
        // check partner tags; retry on miss
        const unsigned int tg = (unsigned int)t;
        for (;;) {
          const bool ok = (((q0 >> 16) & 0xFFFFu) == tg) & ((unsigned)(q0 >> 48) == tg) &
                          (((q1 >> 16) & 0xFFFFu) == tg) & ((unsigned)(q1 >> 48) == tg);
          if (__all(ok)) break;
          __builtin_amdgcn_s_sleep(1);
          q0 = ld64(sb); q1 = ld64(sb + 2);
        }
        const unsigned int lo = (unsigned)(q0 & 0xFFFF) | (((unsigned)(q0 >> 32) & 0xFFFF) << 16);
        const unsigned int hi = (unsigned)(q1 & 0xFFFF) | (((unsigned)(q1 >> 32) & 0xFFFF) << 16);
        *(uint2*)(Ab + ((srow * 512 + (po * 128 + spc) * 2) ^ ((srow & 7) << 4))) = (uint2){lo, hi};
      }
      wg_bar();   // partner staged
      if (t > 0) {
        s16x8 ap[4];
#pragma unroll
        for (int i = 0; i < 4; ++i) {
          const int ks = po * 4 + i;
          ap[i] = *(const s16x8*)(Ab + ((arow * 512 + (ks * 32 + kgrp * 8) * 2) ^ ((arow & 7) << 4)));
        }
#pragma unroll
        for (int i = 0; i < 4; ++i)
#pragma unroll
          for (int n = 0; n < 4; ++n) acc[n] = MFMA(ap[i], bw[n * 8 + 4 + i], acc[n]);
      }
      // EW per-lane; publish tagged (no drain) + own-half h into LDS
      const unsigned int tagw = (unsigned)(t + 1) << 16;
#pragma unroll
      for (int r = 0; r < 4; ++r) {
        const int row = kgrp * 4 + r;
        const float gi = acc[0][r] + bE[0] + xr[r] * xE[0];
        const float gf = acc[1][r] + bE[1] + xr[r] * xE[1];
        const float gg = acc[2][r] + bE[2] + xr[r] * xE[2];
        const float go = acc[3][r] + bE[3] + xr[r] * xE[3];
        cL[r] = sigm(gf) * cL[r] + sigm(gi) * tanh_f(gg);
        const float hv = sigm(go) * tanh_f(cL[r]);
        const unsigned short hb = f2bf(hv);
        st32(sr + (t & (D0 - 1)) * 4096 + row * 256 + U, tagw | hb);
        *(unsigned short*)(Ab + ((row * 512 + U * 2) ^ ((row & 7) << 4))) = hb;
      }
    }
  } else {
    // ========== LAYER 1: 4 WGs/group x 64 units, K=512 (Wx1|Wh1), shfl EW ==========
    const int idx = bid - 8, g = idx >> 2, q = idx & 3;
    const int ub  = q * 64;
    const int go_ = u16 >> 2;                    // lane's MFMA gate
    const int lu  = u16 & 3;                     // local unit in quad
    // ntile nt: unit(nt) = ub + w*8 + nt*4 + lu  (independent of go_)
    s16x8 bw[2][16];
#pragma unroll
    for (int nt = 0; nt < 2; ++nt)
#pragma unroll
      for (int ks = 0; ks < 16; ++ks) {
        const int col = go_ * 256 + ub + w * 8 + nt * 4 + lu;
#pragma unroll
        for (int j = 0; j < 8; ++j) {
          const int k = (ks & 7) * 32 + kgrp * 8 + j;
          bw[nt][ks][j] = (short)f2bf((ks < 8) ? Wx1[(size_t)k * 1024 + col]
                                               : Wh1[(size_t)k * 1024 + col]);
        }
      }
    float bE[2];                                 // this lane's gate bias per ntile
#pragma unroll
    for (int nt = 0; nt < 2; ++nt) bE[nt] = b1v[go_ * 256 + ub + w * 8 + nt * 4 + lu];

    unsigned int* sr = seqring + (size_t)g * D0 * 4096;
    unsigned int* hr = h1ring  + (size_t)g * D1 * 4096;
    const int srow = tid >> 5, sc8 = (tid & 31) * 8;    // stage: 8 u32/thread
    float cL[2][4] = {{0,0,0,0},{0,0,0,0}};
    float hs[2][4] = {{0,0,0,0},{0,0,0,0}};
    unsigned long long qh0[4], qh1[4];

    // prologue: prefetch h0(0) (L0 ahead -> valid by the time we check)
    {
      const unsigned int* sb = sr + srow * 256 + sc8;
#pragma unroll
      for (int i = 0; i < 4; ++i) qh0[i] = ld64(sb + i * 2);
    }

    for (int t = 0; t < TT; ++t) {
      if ((t & 3) == 3 && tid == 0) st32i(&prog[(g * 4 + q) * 16], t);
      // issue h1(t-1) loads NOW (peers' stores get h0-phase time to land)
      const unsigned int* sbh1 = hr + ((t - 1) & (D1 - 1)) * 4096 + srow * 256 + sc8;
      if (t > 0) {
#pragma unroll
        for (int i = 0; i < 4; ++i) qh1[i] = ld64(sbh1 + i * 2);
      }
      // ---- h0(t): check prefetched (L0 ahead -> first check passes) ----
      {
        const unsigned int* sb = sr + (t & (D0 - 1)) * 4096 + srow * 256 + sc8;
        const unsigned int tg = (unsigned int)(t + 1);
        for (;;) {
          bool ok = true;
#pragma unroll
          for (int i = 0; i < 4; ++i)
            ok &= (((qh0[i] >> 16) & 0xFFFFu) == tg) & ((unsigned)(qh0[i] >> 48) == tg);
          if (__all(ok)) break;
          __builtin_amdgcn_s_sleep(1);
#pragma unroll
          for (int i = 0; i < 4; ++i) qh0[i] = ld64(sb + i * 2);
        }
        unsigned int wv[4];
#pragma unroll
        for (int i = 0; i < 4; ++i)
          wv[i] = (unsigned)(qh0[i] & 0xFFFF) | (((unsigned)(qh0[i] >> 32) & 0xFFFF) << 16);
        *(uint4*)(Ab + ((srow * 512 + sc8 * 2) ^ ((srow & 7) << 4))) =
            (uint4){wv[0], wv[1], wv[2], wv[3]};
      }
      wg_bar();   // h0 staged (also: Ab safe -- all waves done with t-1 MFMAs)
      f32x4 acc0 = {0,0,0,0}, acc1 = {0,0,0,0};
      {
        s16x8 a[8];
#pragma unroll
        for (int ks = 0; ks < 8; ++ks)
          a[ks] = *(const s16x8*)(Ab + ((arow * 512 + (ks * 32 + kgrp * 8) * 2) ^ ((arow & 7) << 4)));
#pragma unroll
        for (int ks = 0; ks < 8; ++ks) {
          acc0 = MFMA(a[ks], bw[0][ks], acc0);
          acc1 = MFMA(a[ks], bw[1][ks], acc1);
        }
      }
      // ---- h1(t-1): check (issued at top, ~600cy ago); stage; MFMA ----
      if (t > 0) {
        const unsigned int tg = (unsigned int)t;
        for (;;) {
          bool ok = true;
#pragma unroll
          for (int i = 0; i < 4; ++i)
            ok &= (((qh1[i] >> 16) & 0xFFFFu) == tg) & ((unsigned)(qh1[i] >> 48) == tg);
          if (__all(ok)) break;
          __builtin_amdgcn_s_sleep(1);
#pragma unroll
          for (int i = 0; i < 4; ++i) qh1[i] = ld64(sbh1 + i * 2);
        }
        unsigned int wv[4];
#pragma unroll
        for (int i = 0; i < 4; ++i)
          wv[i] = (unsigned)(qh1[i] & 0xFFFF) | (((unsigned)(qh1[i] >> 32) & 0xFFFF) << 16);
        *(uint4*)(Ab1 + ((srow * 512 + sc8 * 2) ^ ((srow & 7) << 4))) =
            (uint4){wv[0], wv[1], wv[2], wv[3]};
      }
      wg_bar();   // h1 staged
      if (t > 0) {
        s16x8 a[8];
#pragma unroll
        for (int kk = 0; kk < 8; ++kk)
          a[kk] = *(const s16x8*)(Ab1 + ((arow * 512 + (kk * 32 + kgrp * 8) * 2) ^ ((arow & 7) << 4)));
#pragma unroll
        for (int kk = 0; kk < 8; ++kk) {
          acc0 = MFMA(a[kk], bw[0][8 + kk], acc0);
          acc1 = MFMA(a[kk], bw[1][8 + kk], acc1);
        }
      }
      // ---- EW via shfl quad gather (r5-verified decode); all lanes redundant x4 ----
      const unsigned int tagw = (unsigned)(t + 1) << 16;
      const bool b0 = go_ & 1, b1 = go_ & 2;
#pragma unroll
      for (int nt = 0; nt < 2; ++nt) {
        f32x4& an = (nt == 0) ? acc0 : acc1;
#pragma unroll
        for (int r = 0; r < 4; ++r) {
          const float av = an[r] + bE[nt];
          const float Bv = __shfl_xor(av, 4);
          const float Cv = __shfl_xor(av, 8);
          const float Dv = __shfl_xor(av, 12);
          const float e0 = b0 ? Bv : av,  e1 = b0 ? av : Bv;
          const float f0 = b0 ? Dv : Cv,  f1 = b0 ? Cv : Dv;
          const float gi = (b1 ? f0 : e0);
          const float gf = (b1 ? f1 : e1);
          const float gg = (b1 ? e0 : f0);
          const float go = (b1 ? e1 : f1);
          cL[nt][r] = sigm(gf) * cL[nt][r] + sigm(gi) * tanh_f(gg);
          const float hv = sigm(go) * tanh_f(cL[nt][r]);
          hs[nt][r] += hv;
          if (u16 < 4)
            st32(hr + (t & (D1 - 1)) * 4096 + (kgrp * 4 + r) * 256 + ub + w * 8 + nt * 4 + lu,
                 tagw | f2bf(hv));
        }
      }
      // prefetch h0(t+1) (L0 far ahead -> lands valid)
      {
        const unsigned int* sb = sr + ((t + 1) & (D0 - 1)) * 4096 + srow * 256 + sc8;
#pragma unroll
        for (int i = 0; i < 4; ++i) qh0[i] = ld64(sb + i * 2);
      }
    }
    if (u16 < 4) {
#pragma unroll
      for (int nt = 0; nt < 2; ++nt)
#pragma unroll
        for (int r = 0; r < 4; ++r)
          hmean[(size_t)(g * 16 + kgrp * 4 + r) * HH + ub + w * 8 + nt * 4 + lu] =
              hs[nt][r] * (1.f / TT);
    }
  }
}

__global__ __launch_bounds__(256)
void mlp_kernel(const float* __restrict__ theta, const float* __restrict__ Wtp,
                const float* __restrict__ btp, const float* __restrict__ Wl1,
                const float* __restrict__ bl1, const float* __restrict__ Wl2,
                const float* __restrict__ bl2, const float* __restrict__ Wo,
                const float* __restrict__ bo, const float* __restrict__ hmean,
                float* __restrict__ out)
{
  const int b = blockIdx.x;
  const int j = threadIdx.x;
  __shared__ float z[2 * HH];
  __shared__ float z1s[HH];
  __shared__ float red[256];

  float tp = btp[j];
#pragma unroll
  for (int d = 0; d < 5; ++d) tp += theta[b * 5 + d] * Wtp[d * HH + j];
  z[j] = hmean[(size_t)b * HH + j];
  z[HH + j] = tp;
  __syncthreads();

  float a1 = bl1[j];
  for (int k = 0; k < 2 * HH; ++k) a1 += z[k] * Wl1[(size_t)k * 256 + j];
  a1 = (a1 > 0.f) ? a1 : (__expf(a1) - 1.f);
  z1s[j] = a1;
  __syncthreads();

  float a2 = bl2[j];
  for (int k = 0; k < HH; ++k) a2 += z1s[k] * Wl2[(size_t)k * 256 + j];
  a2 = (a2 > 0.f) ? a2 : (__expf(a2) - 1.f);
  red[j] = a2 * Wo[j];
  __syncthreads();
  for (int s = 128; s > 0; s >>= 1) {
    if (j < s) red[j] += red[j + s];
    __syncthreads();
  }
  if (j == 0) out[b] = red[0] + bo[0];
}

extern "C" void kernel_launch(void* const* d_in, const int* in_sizes, int n_in,
                              void* d_out, int out_size, void* d_ws, size_t ws_size,
                              hipStream_t stream) {
  const float* x    = (const float*)d_in[0];
  const float* theta= (const float*)d_in[1];
  const float* Wx0  = (const float*)d_in[2];
  const float* Wh0  = (const float*)d_in[3];
  const float* b0   = (const float*)d_in[4];
  const float* Wx1  = (const float*)d_in[5];
  const float* Wh1  = (const float*)d_in[6];
  const float* b1   = (const float*)d_in[7];
  const float* Wtp  = (const float*)d_in[8];
  const float* btp  = (const float*)d_in[9];
  const float* Wl1  = (const float*)d_in[10];
  const float* bl1  = (const float*)d_in[11];
  const float* Wl2  = (const float*)d_in[12];
  const float* bl2  = (const float*)d_in[13];
  const float* Wo   = (const float*)d_in[14];
  const float* bo   = (const float*)d_in[15];

  // ws: prog 8KB | seqring [4][16][16][256] u32 1MB | h1ring [4][4][16][256] u32 256KB
  //     | hmean 64KB | xT 512KB.  prog+rings memset each launch (tag 0 never valid).
  char* ws = (char*)d_ws;
  int* prog             = (int*)ws;
  unsigned int* seqring = (unsigned int*)(ws + 8192);
  unsigned int* h1ring  = (unsigned int*)(ws + 8192 + 1048576);
  float* hmean          = (float*)(ws + 8192 + 1048576 + 262144);
  float* xT             = (float*)(ws + 8192 + 1048576 + 262144 + 65536);
  const size_t WS_NEED = 8192ull + 1048576 + 262144 + 65536 + 524288;
  if (ws_size < WS_NEED) return;

  hipMemsetAsync(d_ws, 0, 8192 + 1048576 + 262144, stream);

  xt_kernel<<<dim3((BB * TT) / 256), dim3(256), 0, stream>>>(x, xT);
  lstm_kernel<<<dim3(24), dim3(512), 0, stream>>>(
      Wx0, Wh0, b0, Wx1, Wh1, b1, xT, seqring, h1ring, hmean, prog);
  mlp_kernel<<<dim3(BB), dim3(256), 0, stream>>>(
      theta, Wtp, btp, Wl1, bl1, Wl2, bl2, Wo, bo, hmean, (float*)d_out);
}

// Round 12
// 6899.721 us; speedup vs baseline: 1.8295x; 1.8295x over previous
//
#include <hip/hip_runtime.h>
#include <hip/hip_bf16.h>

// LSTMModel_with_theta: B=64, T=2048, H=256, 2-layer LSTM -> mean_t -> MLP.
//
// Round 12: r10 (6.19ms best) EXACTLY, plus one theme: two-deep load pipeline
// on the peer exchanges.
//  - r11 post-mortem: 3 changes at once, -2x. Most mechanistic suspect: EW
//    publish de-coalescing (128 lanes x 8 scattered dwords vs r10's 1024
//    contiguous) stretched publish-to-MALL time -> peers retried more.
//    Reverted wholesale; r10's coalesced publishes restored.
//  - New: keep r10's end-of-step prefetch (sometimes valid for free) AND issue
//    an eager backup reload at step top (~500cy in flight by check time).
//    Check adopts prefetch -> backup -> fresh reloads, NO s_sleep in retry
//    (sleep quantum added latency per retry). L0 partner + L1 h1 paths.

#define BB 64
#define TT 2048
#define HH 256
#define D0 16
#define D1 4

typedef short s16x8 __attribute__((ext_vector_type(8)));
typedef float f32x4 __attribute__((ext_vector_type(4)));

__device__ inline unsigned short f2bf(float f) {
  unsigned u = __float_as_uint(f);
  u += 0x7fff + ((u >> 16) & 1);          // RNE
  return (unsigned short)(u >> 16);
}
__device__ inline float sigm(float x) { return 1.f / (1.f + __expf(-x)); }
__device__ inline float tanh_f(float x) { return 1.f - 2.f / (__expf(2.f * x) + 1.f); }

__device__ inline unsigned long long ld64(const unsigned int* p) {
  return __hip_atomic_load((const unsigned long long*)p, __ATOMIC_RELAXED,
                           __HIP_MEMORY_SCOPE_AGENT);
}
__device__ inline void st32(unsigned int* p, unsigned int v) {
  __hip_atomic_store(p, v, __ATOMIC_RELAXED, __HIP_MEMORY_SCOPE_AGENT);
}
__device__ inline void st32i(int* p, int v) {
  __hip_atomic_store(p, v, __ATOMIC_RELAXED, __HIP_MEMORY_SCOPE_AGENT);
}
__device__ inline int ld32i(const int* p) {
  return __hip_atomic_load(p, __ATOMIC_RELAXED, __HIP_MEMORY_SCOPE_AGENT);
}
__device__ inline void wg_bar() {
  asm volatile("s_waitcnt lgkmcnt(0)" ::: "memory");
  __builtin_amdgcn_sched_barrier(0);
  __builtin_amdgcn_s_barrier();
  __builtin_amdgcn_sched_barrier(0);
}
__device__ inline bool tag2ok(unsigned long long q, unsigned int tg) {
  return (((q >> 16) & 0xFFFFu) == tg) & ((unsigned)(q >> 48) == tg);
}

#define MFMA(a, b, c) __builtin_amdgcn_mfma_f32_16x16x32_bf16((a), (b), (c), 0, 0, 0)

__global__ void xt_kernel(const float* __restrict__ x, float* __restrict__ xT) {
  int i = blockIdx.x * 256 + threadIdx.x;   // 131072 total
  int b = i & 63, t = i >> 6;
  xT[(size_t)t * BB + b] = x[(size_t)b * TT + t];
}

__global__ __launch_bounds__(512, 1)
void lstm_kernel(const float* __restrict__ Wx0, const float* __restrict__ Wh0,
                 const float* __restrict__ b0v,
                 const float* __restrict__ Wx1, const float* __restrict__ Wh1,
                 const float* __restrict__ b1v,
                 const float* __restrict__ xT,
                 unsigned int* __restrict__ seqring,   // [4][D0][16][256] tagged u32
                 unsigned int* __restrict__ h1ring,    // [4][D1][16][256] tagged u32
                 float* __restrict__ hmean, int* prog)
{
  __shared__ __align__(16) char Ab [8192];       // [16 rows][256 units] bf16, swizzled
  __shared__ __align__(16) char Ab1[8192];       // L1: h1(t-1)
  __shared__ float gbuf[16][4][66];              // L1 gate gather

  const int tid  = threadIdx.x;
  const int lane = tid & 63;
  const int w    = tid >> 6;        // wave 0..7
  const int u16  = lane & 15;
  const int kgrp = lane >> 4;
  const int arow = lane & 15;
  const int bid  = blockIdx.x;

  if (bid < 8) {
    // ========== LAYER 0: 2 WGs/group x 128 units, K=256 ==========
    const int g = bid >> 1, ho = bid & 1, po = 1 - ho;
    const int U = ho * 128 + w * 16 + u16;       // lane's unit (all 4 gates)
    // bw by PHASE (static reg indices): [n*8+0..3]=own ks, [n*8+4..7]=partner ks
    s16x8 bw[32];
#pragma unroll
    for (int n = 0; n < 4; ++n)
#pragma unroll
      for (int ph = 0; ph < 2; ++ph)
#pragma unroll
        for (int i = 0; i < 4; ++i) {
          const int ks = (ph == 0 ? ho : po) * 4 + i;   // runtime, address-only
          const int col = n * 256 + U;
#pragma unroll
          for (int j = 0; j < 8; ++j)
            bw[n * 8 + ph * 4 + i][j] =
                (short)f2bf(Wh0[(size_t)(ks * 32 + kgrp * 8 + j) * 1024 + col]);
        }
    float bE[4], xE[4];
#pragma unroll
    for (int n = 0; n < 4; ++n) { bE[n] = b0v[n * 256 + U]; xE[n] = Wx0[n * 256 + U]; }

    unsigned int* sr = seqring + (size_t)g * D0 * 4096;
    const int srow = tid >> 5, spc = (tid & 31) * 4;    // partner stage: 4 u32/thread
    float cL[4] = {0.f, 0.f, 0.f, 0.f};
    unsigned long long pq0 = 0, pq1 = 0;                // prefetched partner h

    for (int t = 0; t < TT; ++t) {
      if ((t & 7) == 0 && t >= 16 && tid < 4)           // L1 back-pressure (coarse)
        while (ld32i(&prog[(g * 4 + tid) * 16]) < t - 8) __builtin_amdgcn_s_sleep(8);
      wg_bar();   // top: EW(t-1) LDS writes visible

      // eager backup reload (in flight across own-MFMA section) + x loads
      const unsigned int* sb = sr + ((t - 1) & (D0 - 1)) * 4096 + srow * 256 + po * 128 + spc;
      unsigned long long r0 = 0, r1 = 0;
      if (t > 0) { r0 = ld64(sb); r1 = ld64(sb + 2); }
      float xr[4];
#pragma unroll
      for (int r = 0; r < 4; ++r) xr[r] = xT[(size_t)t * BB + g * 16 + kgrp * 4 + r];

      f32x4 acc[4] = {{0,0,0,0},{0,0,0,0},{0,0,0,0},{0,0,0,0}};
      if (t > 0) {
        // own-half MFMAs from LDS (cover the backup-load flight)
        s16x8 ao[4];
#pragma unroll
        for (int i = 0; i < 4; ++i) {
          const int ks = ho * 4 + i;
          ao[i] = *(const s16x8*)(Ab + ((arow * 512 + (ks * 32 + kgrp * 8) * 2) ^ ((arow & 7) << 4)));
        }
#pragma unroll
        for (int i = 0; i < 4; ++i)
#pragma unroll
          for (int n = 0; n < 4; ++n) acc[n] = MFMA(ao[i], bw[n * 8 + i], acc[n]);
        // check: prefetched -> adopt backup -> fresh reloads (no sleep)
        const unsigned int tg = (unsigned int)t;
        unsigned long long q0 = pq0, q1 = pq1;
        for (;;) {
          if (__all(tag2ok(q0, tg) & tag2ok(q1, tg))) break;
          q0 = r0; q1 = r1;                 // adopt in-flight
          r0 = ld64(sb); r1 = ld64(sb + 2); // keep one in flight
        }
        const unsigned int lo = (unsigned)(q0 & 0xFFFF) | (((unsigned)(q0 >> 32) & 0xFFFF) << 16);
        const unsigned int hi = (unsigned)(q1 & 0xFFFF) | (((unsigned)(q1 >> 32) & 0xFFFF) << 16);
        *(uint2*)(Ab + ((srow * 512 + (po * 128 + spc) * 2) ^ ((srow & 7) << 4))) = (uint2){lo, hi};
      }
      wg_bar();   // partner staged
      if (t > 0) {
        s16x8 ap[4];
#pragma unroll
        for (int i = 0; i < 4; ++i) {
          const int ks = po * 4 + i;
          ap[i] = *(const s16x8*)(Ab + ((arow * 512 + (ks * 32 + kgrp * 8) * 2) ^ ((arow & 7) << 4)));
        }
#pragma unroll
        for (int i = 0; i < 4; ++i)
#pragma unroll
          for (int n = 0; n < 4; ++n) acc[n] = MFMA(ap[i], bw[n * 8 + 4 + i], acc[n]);
      }
      // EW per-lane; publish tagged (no drain) + own-half h into LDS
      const unsigned int tagw = (unsigned)(t + 1) << 16;
#pragma unroll
      for (int r = 0; r < 4; ++r) {
        const int row = kgrp * 4 + r;
        const float gi = acc[0][r] + bE[0] + xr[r] * xE[0];
        const float gf = acc[1][r] + bE[1] + xr[r] * xE[1];
        const float gg = acc[2][r] + bE[2] + xr[r] * xE[2];
        const float go = acc[3][r] + bE[3] + xr[r] * xE[3];
        cL[r] = sigm(gf) * cL[r] + sigm(gi) * tanh_f(gg);
        const float hv = sigm(go) * tanh_f(cL[r]);
        const unsigned short hb = f2bf(hv);
        st32(sr + (t & (D0 - 1)) * 4096 + row * 256 + U, tagw | hb);
        *(unsigned short*)(Ab + ((row * 512 + U * 2) ^ ((row & 7) << 4))) = hb;
      }
      // prefetch partner h(t) (sometimes valid by next step's check -> free)
      {
        const unsigned int* pb = sr + (t & (D0 - 1)) * 4096 + srow * 256 + po * 128 + spc;
        pq0 = ld64(pb); pq1 = ld64(pb + 2);
      }
    }
  } else {
    // ========== LAYER 1: 4 WGs/group x 64 units, K=512 (Wx1|Wh1) ==========
    const int idx = bid - 8, g = idx >> 2, q = idx & 3;
    const int gp = w >> 2;            // gate pair
    const int uo = (w & 3) * 16;      // unit offset in WG's 64
    const int ub = q * 64;
    s16x8 bw[2][16];                  // static idx only
#pragma unroll
    for (int nt = 0; nt < 2; ++nt)
#pragma unroll
      for (int ks = 0; ks < 16; ++ks) {
        const int col = (2 * gp + nt) * 256 + ub + uo + u16;
#pragma unroll
        for (int j = 0; j < 8; ++j) {
          const int k = (ks & 7) * 32 + kgrp * 8 + j;
          bw[nt][ks][j] = (short)f2bf((ks < 8) ? Wx1[(size_t)k * 1024 + col]
                                               : Wh1[(size_t)k * 1024 + col]);
        }
      }
    const int eur = tid >> 5, eu2 = (tid & 31) * 2;
    float bE[4][2];
#pragma unroll
    for (int ga = 0; ga < 4; ++ga)
#pragma unroll
      for (int uu = 0; uu < 2; ++uu)
        bE[ga][uu] = b1v[ga * 256 + ub + eu2 + uu];

    unsigned int* sr = seqring + (size_t)g * D0 * 4096;
    unsigned int* hr = h1ring  + (size_t)g * D1 * 4096;
    const int srow = tid >> 5, sc8 = (tid & 31) * 8;    // stage: 8 u32/thread
    float cL[2] = {0.f, 0.f}, hs[2] = {0.f, 0.f};
    unsigned long long qh0[4], qh1[4];

    // prologue: prefetch h0(0)
    {
      const unsigned int* sb = sr + srow * 256 + sc8;
#pragma unroll
      for (int i = 0; i < 4; ++i) qh0[i] = ld64(sb + i * 2);
    }

    for (int t = 0; t < TT; ++t) {
      if ((t & 3) == 3 && tid == 0) st32i(&prog[(g * 4 + q) * 16], t);
      // eager backup reload of h1(t-1) (in flight across the h0 phase)
      const unsigned int* sbh1 = hr + ((t - 1) & (D1 - 1)) * 4096 + srow * 256 + sc8;
      unsigned long long rh1[4];
      if (t > 0) {
#pragma unroll
        for (int i = 0; i < 4; ++i) rh1[i] = ld64(sbh1 + i * 2);
      }
      // ---- h0(t): check prefetched (L0 runs ahead -> first check passes) ----
      {
        const unsigned int* sb = sr + (t & (D0 - 1)) * 4096 + srow * 256 + sc8;
        const unsigned int tg = (unsigned int)(t + 1);
        for (;;) {
          bool ok = true;
#pragma unroll
          for (int i = 0; i < 4; ++i) ok &= tag2ok(qh0[i], tg);
          if (__all(ok)) break;
#pragma unroll
          for (int i = 0; i < 4; ++i) qh0[i] = ld64(sb + i * 2);
        }
        unsigned int wv[4];
#pragma unroll
        for (int i = 0; i < 4; ++i)
          wv[i] = (unsigned)(qh0[i] & 0xFFFF) | (((unsigned)(qh0[i] >> 32) & 0xFFFF) << 16);
        *(uint4*)(Ab + ((srow * 512 + sc8 * 2) ^ ((srow & 7) << 4))) =
            (uint4){wv[0], wv[1], wv[2], wv[3]};
      }
      wg_bar();   // h0 staged
      f32x4 acc0 = {0,0,0,0}, acc1 = {0,0,0,0};
      {
        s16x8 a[8];
#pragma unroll
        for (int ks = 0; ks < 8; ++ks)
          a[ks] = *(const s16x8*)(Ab + ((arow * 512 + (ks * 32 + kgrp * 8) * 2) ^ ((arow & 7) << 4)));
#pragma unroll
        for (int ks = 0; ks < 8; ++ks) {
          acc0 = MFMA(a[ks], bw[0][ks], acc0);
          acc1 = MFMA(a[ks], bw[1][ks], acc1);
        }
      }
      // ---- h1(t-1): check prefetched -> adopt backup -> fresh (no sleep) ----
      if (t > 0) {
        const unsigned int tg = (unsigned int)t;
        for (;;) {
          bool ok = true;
#pragma unroll
          for (int i = 0; i < 4; ++i) ok &= tag2ok(qh1[i], tg);
          if (__all(ok)) break;
#pragma unroll
          for (int i = 0; i < 4; ++i) qh1[i] = rh1[i];      // adopt in-flight
#pragma unroll
          for (int i = 0; i < 4; ++i) rh1[i] = ld64(sbh1 + i * 2);
        }
        unsigned int wv[4];
#pragma unroll
        for (int i = 0; i < 4; ++i)
          wv[i] = (unsigned)(qh1[i] & 0xFFFF) | (((unsigned)(qh1[i] >> 32) & 0xFFFF) << 16);
        *(uint4*)(Ab1 + ((srow * 512 + sc8 * 2) ^ ((srow & 7) << 4))) =
            (uint4){wv[0], wv[1], wv[2], wv[3]};
      }
      wg_bar();   // h1 staged
      if (t > 0) {
        s16x8 a[8];
#pragma unroll
        for (int kk = 0; kk < 8; ++kk)
          a[kk] = *(const s16x8*)(Ab1 + ((arow * 512 + (kk * 32 + kgrp * 8) * 2) ^ ((arow & 7) << 4)));
#pragma unroll
        for (int kk = 0; kk < 8; ++kk) {
          acc0 = MFMA(a[kk], bw[0][8 + kk], acc0);
          acc1 = MFMA(a[kk], bw[1][8 + kk], acc1);
        }
      }
#pragma unroll
      for (int r = 0; r < 4; ++r) {
        gbuf[kgrp * 4 + r][2 * gp + 0][uo + u16] = acc0[r];
        gbuf[kgrp * 4 + r][2 * gp + 1][uo + u16] = acc1[r];
      }
      wg_bar();   // gates gathered

      unsigned short hb[2];
#pragma unroll
      for (int uu = 0; uu < 2; ++uu) {
        const int u = eu2 + uu;
        const float gi = gbuf[eur][0][u] + bE[0][uu];
        const float gf = gbuf[eur][1][u] + bE[1][uu];
        const float gg = gbuf[eur][2][u] + bE[2][uu];
        const float go = gbuf[eur][3][u] + bE[3][uu];
        cL[uu] = sigm(gf) * cL[uu] + sigm(gi) * tanh_f(gg);
        const float hv = sigm(go) * tanh_f(cL[uu]);
        hs[uu] += hv;
        hb[uu] = f2bf(hv);
      }
      const unsigned int tagw = (unsigned)(t + 1) << 16;
      st32(hr + (t & (D1 - 1)) * 4096 + eur * 256 + ub + eu2,     tagw | hb[0]);
      st32(hr + (t & (D1 - 1)) * 4096 + eur * 256 + ub + eu2 + 1, tagw | hb[1]);
      // ---- prefetch for next step ----
      {
        const unsigned int* sb = sr + ((t + 1) & (D0 - 1)) * 4096 + srow * 256 + sc8;
#pragma unroll
        for (int i = 0; i < 4; ++i) qh0[i] = ld64(sb + i * 2);
        const unsigned int* hb2 = hr + (t & (D1 - 1)) * 4096 + srow * 256 + sc8;
#pragma unroll
        for (int i = 0; i < 4; ++i) qh1[i] = ld64(hb2 + i * 2);
      }
    }
#pragma unroll
    for (int uu = 0; uu < 2; ++uu)
      hmean[(size_t)(g * 16 + eur) * HH + ub + eu2 + uu] = hs[uu] * (1.f / TT);
  }
}

__global__ __launch_bounds__(256)
void mlp_kernel(const float* __restrict__ theta, const float* __restrict__ Wtp,
                const float* __restrict__ btp, const float* __restrict__ Wl1,
                const float* __restrict__ bl1, const float* __restrict__ Wl2,
                const float* __restrict__ bl2, const float* __restrict__ Wo,
                const float* __restrict__ bo, const float* __restrict__ hmean,
                float* __restrict__ out)
{
  const int b = blockIdx.x;
  const int j = threadIdx.x;
  __shared__ float z[2 * HH];
  __shared__ float z1s[HH];
  __shared__ float red[256];

  float tp = btp[j];
#pragma unroll
  for (int d = 0; d < 5; ++d) tp += theta[b * 5 + d] * Wtp[d * HH + j];
  z[j] = hmean[(size_t)b * HH + j];
  z[HH + j] = tp;
  __syncthreads();

  float a1 = bl1[j];
  for (int k = 0; k < 2 * HH; ++k) a1 += z[k] * Wl1[(size_t)k * 256 + j];
  a1 = (a1 > 0.f) ? a1 : (__expf(a1) - 1.f);
  z1s[j] = a1;
  __syncthreads();

  float a2 = bl2[j];
  for (int k = 0; k < HH; ++k) a2 += z1s[k] * Wl2[(size_t)k * 256 + j];
  a2 = (a2 > 0.f) ? a2 : (__expf(a2) - 1.f);
  red[j] = a2 * Wo[j];
  __syncthreads();
  for (int s = 128; s > 0; s >>= 1) {
    if (j < s) red[j] += red[j + s];
    __syncthreads();
  }
  if (j == 0) out[b] = red[0] + bo[0];
}

extern "C" void kernel_launch(void* const* d_in, const int* in_sizes, int n_in,
                              void* d_out, int out_size, void* d_ws, size_t ws_size,
                              hipStream_t stream) {
  const float* x    = (const float*)d_in[0];
  const float* theta= (const float*)d_in[1];
  const float* Wx0  = (const float*)d_in[2];
  const float* Wh0  = (const float*)d_in[3];
  const float* b0   = (const float*)d_in[4];
  const float* Wx1  = (const float*)d_in[5];
  const float* Wh1  = (const float*)d_in[6];
  const float* b1   = (const float*)d_in[7];
  const float* Wtp  = (const float*)d_in[8];
  const float* btp  = (const float*)d_in[9];
  const float* Wl1  = (const float*)d_in[10];
  const float* bl1  = (const float*)d_in[11];
  const float* Wl2  = (const float*)d_in[12];
  const float* bl2  = (const float*)d_in[13];
  const float* Wo   = (const float*)d_in[14];
  const float* bo   = (const float*)d_in[15];

  // ws: prog 8KB | seqring [4][16][16][256] u32 1MB | h1ring [4][4][16][256] u32 256KB
  //     | hmean 64KB | xT 512KB.  prog+rings memset each launch (tag 0 never valid).
  char* ws = (char*)d_ws;
  int* prog             = (int*)ws;
  unsigned int* seqring = (unsigned int*)(ws + 8192);
  unsigned int* h1ring  = (unsigned int*)(ws + 8192 + 1048576);
  float* hmean          = (float*)(ws + 8192 + 1048576 + 262144);
  float* xT             = (float*)(ws + 8192 + 1048576 + 262144 + 65536);
  const size_t WS_NEED = 8192ull + 1048576 + 262144 + 65536 + 524288;
  if (ws_size < WS_NEED) return;

  hipMemsetAsync(d_ws, 0, 8192 + 1048576 + 262144, stream);

  xt_kernel<<<dim3((BB * TT) / 256), dim3(256), 0, stream>>>(x, xT);
  lstm_kernel<<<dim3(24), dim3(512), 0, stream>>>(
      Wx0, Wh0, b0, Wx1, Wh1, b1, xT, seqring, h1ring, hmean, prog);
  mlp_kernel<<<dim3(BB), dim3(256), 0, stream>>>(
      theta, Wtp, btp, Wl1, bl1, Wl2, bl2, Wo, bo, hmean, (float*)d_out);
}